// Round 4
// baseline (264.528 us; speedup 1.0000x reference)
//
#include <hip/hip_runtime.h>
#include <hip/hip_bf16.h>

#define D 128
#define LN_EPS 1e-5f
#define RPB 8        // rows per block in fused kernel

// ---------------------------------------------------------------------------
// setup: zero counts[N] and transpose W -> WT in one dispatch
// ---------------------------------------------------------------------------
__global__ void setup_kernel(const float* __restrict__ W, float* __restrict__ WT,
                             int* __restrict__ counts, int N) {
    int i = blockIdx.x * blockDim.x + threadIdx.x;
    if (i < N) counts[i] = 0;
    if (i < D * D) WT[(i & (D - 1)) * D + (i >> 7)] = W[i];
}

// ---------------------------------------------------------------------------
// histogram of edge rows: 8 edges/thread, 8 independent atomics in flight
// ---------------------------------------------------------------------------
__global__ void hist_kernel(const int* __restrict__ edge_row,
                            int* __restrict__ counts, int E) {
    int i = blockIdx.x * blockDim.x + threadIdx.x;
    int e = i * 8;
    if (e + 7 < E) {
        int4 a = *(const int4*)(edge_row + e);
        int4 b = *(const int4*)(edge_row + e + 4);
        atomicAdd(&counts[a.x], 1);
        atomicAdd(&counts[a.y], 1);
        atomicAdd(&counts[a.z], 1);
        atomicAdd(&counts[a.w], 1);
        atomicAdd(&counts[b.x], 1);
        atomicAdd(&counts[b.y], 1);
        atomicAdd(&counts[b.z], 1);
        atomicAdd(&counts[b.w], 1);
    } else {
        for (; e < E; ++e) atomicAdd(&counts[edge_row[e]], 1);
    }
}

// ---------------------------------------------------------------------------
// scan1: per-256-block inclusive scan -> exclusive offsets + block sums
// ---------------------------------------------------------------------------
__global__ void scan1(const int* __restrict__ counts, int* __restrict__ excl,
                      int* __restrict__ bsums, int n) {
    __shared__ int tmp[2][256];
    int t = threadIdx.x;
    int i = blockIdx.x * 256 + t;
    int v = (i < n) ? counts[i] : 0;
    tmp[0][t] = v;
    __syncthreads();
    int buf = 0;
    for (int off = 1; off < 256; off <<= 1) {
        int x = tmp[buf][t];
        if (t >= off) x += tmp[buf][t - off];
        tmp[1 - buf][t] = x;
        buf ^= 1;
        __syncthreads();
    }
    int incl = tmp[buf][t];
    if (i < n) excl[i] = incl - v;
    if (t == 255) bsums[blockIdx.x] = incl;
}

// ---------------------------------------------------------------------------
// scan23: each block redundantly scans bsums (nb<=256) in LDS, applies its
// exclusive prefix, writes final offsets + cursor copy
// ---------------------------------------------------------------------------
__global__ void scan23(int* __restrict__ excl, const int* __restrict__ bsums,
                       int* __restrict__ cursor, int n, int nb) {
    __shared__ int tmp[2][256];
    __shared__ int prefix;
    int t = threadIdx.x;
    int v = (t < nb) ? bsums[t] : 0;
    tmp[0][t] = v;
    __syncthreads();
    int buf = 0;
    for (int off = 1; off < 256; off <<= 1) {
        int x = tmp[buf][t];
        if (t >= off) x += tmp[buf][t - off];
        tmp[1 - buf][t] = x;
        buf ^= 1;
        __syncthreads();
    }
    if (t == 0) prefix = (blockIdx.x == 0) ? 0 : tmp[buf][blockIdx.x - 1];
    __syncthreads();
    int i = blockIdx.x * 256 + t;
    if (i < n) {
        int o = excl[i] + prefix;
        excl[i] = o;
        cursor[i] = o;
    }
}

// ---------------------------------------------------------------------------
// scatter edges into row-sorted (col,val) pairs: 4 edges/thread,
// 4 independent atomics + 4 stores in flight
// ---------------------------------------------------------------------------
__global__ void scatter_sort(const int* __restrict__ edge_row,
                             const int* __restrict__ edge_col,
                             const float* __restrict__ edge_val,
                             int* __restrict__ cursor,
                             int2* __restrict__ sorted, int E) {
    int i = blockIdx.x * blockDim.x + threadIdx.x;
    int e = i * 4;
    if (e + 3 < E) {
        int4 r = *(const int4*)(edge_row + e);
        int4 c = *(const int4*)(edge_col + e);
        float4 v = *(const float4*)(edge_val + e);
        int p0 = atomicAdd(&cursor[r.x], 1);
        int p1 = atomicAdd(&cursor[r.y], 1);
        int p2 = atomicAdd(&cursor[r.z], 1);
        int p3 = atomicAdd(&cursor[r.w], 1);
        sorted[p0] = make_int2(c.x, __float_as_int(v.x));
        sorted[p1] = make_int2(c.y, __float_as_int(v.y));
        sorted[p2] = make_int2(c.z, __float_as_int(v.z));
        sorted[p3] = make_int2(c.w, __float_as_int(v.w));
    } else {
        for (; e < E; ++e) {
            int p = atomicAdd(&cursor[edge_row[e]], 1);
            sorted[p] = make_int2(edge_col[e], __float_as_int(edge_val[e]));
        }
    }
}

// ---------------------------------------------------------------------------
// fused: gather SpMM (32 thr/row, float4/lane, 8 x-loads in flight) -> LDS ->
// linear (h = s @ W^T + b) -> LayerNorm -> ReLU -> d_out
// ---------------------------------------------------------------------------
__global__ void __launch_bounds__(256) fused_gather_linear(
    const float* __restrict__ x, const int2* __restrict__ sorted,
    const int* __restrict__ offsets,
    const float* __restrict__ WT, const float* __restrict__ b,
    const float* __restrict__ gamma, const float* __restrict__ beta,
    float* __restrict__ out, int N, int E) {
    __shared__ float s[RPB][D];
    __shared__ float mu_s[RPB], inv_s[RPB];
    int t = threadIdx.x;
    int row0 = blockIdx.x * RPB;

    // ---- gather phase ----
    {
        int r = t >> 5;            // 0..7
        int q = t & 31;            // float4 chunk
        int row = row0 + r;
        float4 acc = make_float4(0.f, 0.f, 0.f, 0.f);
        if (row < N) {
            int start = offsets[row];
            int end = (row + 1 < N) ? offsets[row + 1] : E;
            int e = start;
            // peel to even index so int4 (2-edge) loads are 16B-aligned
            if ((e & 1) && e < end) {
                int2 c = sorted[e];
                float4 v = *(const float4*)(x + (size_t)c.x * D + q * 4);
                float w = __int_as_float(c.y);
                acc.x = fmaf(w, v.x, acc.x); acc.y = fmaf(w, v.y, acc.y);
                acc.z = fmaf(w, v.z, acc.z); acc.w = fmaf(w, v.w, acc.w);
                ++e;
            }
            // 8 edges per iteration: 4x int4 edge loads, 8 x-loads in flight
            for (; e + 8 <= end; e += 8) {
                int4 p0 = *(const int4*)(sorted + e);
                int4 p1 = *(const int4*)(sorted + e + 2);
                int4 p2 = *(const int4*)(sorted + e + 4);
                int4 p3 = *(const int4*)(sorted + e + 6);
                const float* xb = x + q * 4;
                float4 v0 = *(const float4*)(xb + (size_t)p0.x * D);
                float4 v1 = *(const float4*)(xb + (size_t)p0.z * D);
                float4 v2 = *(const float4*)(xb + (size_t)p1.x * D);
                float4 v3 = *(const float4*)(xb + (size_t)p1.z * D);
                float4 v4 = *(const float4*)(xb + (size_t)p2.x * D);
                float4 v5 = *(const float4*)(xb + (size_t)p2.z * D);
                float4 v6 = *(const float4*)(xb + (size_t)p3.x * D);
                float4 v7 = *(const float4*)(xb + (size_t)p3.z * D);
                float w0 = __int_as_float(p0.y), w1 = __int_as_float(p0.w);
                float w2 = __int_as_float(p1.y), w3 = __int_as_float(p1.w);
                float w4 = __int_as_float(p2.y), w5 = __int_as_float(p2.w);
                float w6 = __int_as_float(p3.y), w7 = __int_as_float(p3.w);
                acc.x = fmaf(w0, v0.x, acc.x); acc.y = fmaf(w0, v0.y, acc.y);
                acc.z = fmaf(w0, v0.z, acc.z); acc.w = fmaf(w0, v0.w, acc.w);
                acc.x = fmaf(w1, v1.x, acc.x); acc.y = fmaf(w1, v1.y, acc.y);
                acc.z = fmaf(w1, v1.z, acc.z); acc.w = fmaf(w1, v1.w, acc.w);
                acc.x = fmaf(w2, v2.x, acc.x); acc.y = fmaf(w2, v2.y, acc.y);
                acc.z = fmaf(w2, v2.z, acc.z); acc.w = fmaf(w2, v2.w, acc.w);
                acc.x = fmaf(w3, v3.x, acc.x); acc.y = fmaf(w3, v3.y, acc.y);
                acc.z = fmaf(w3, v3.z, acc.z); acc.w = fmaf(w3, v3.w, acc.w);
                acc.x = fmaf(w4, v4.x, acc.x); acc.y = fmaf(w4, v4.y, acc.y);
                acc.z = fmaf(w4, v4.z, acc.z); acc.w = fmaf(w4, v4.w, acc.w);
                acc.x = fmaf(w5, v5.x, acc.x); acc.y = fmaf(w5, v5.y, acc.y);
                acc.z = fmaf(w5, v5.z, acc.z); acc.w = fmaf(w5, v5.w, acc.w);
                acc.x = fmaf(w6, v6.x, acc.x); acc.y = fmaf(w6, v6.y, acc.y);
                acc.z = fmaf(w6, v6.z, acc.z); acc.w = fmaf(w6, v6.w, acc.w);
                acc.x = fmaf(w7, v7.x, acc.x); acc.y = fmaf(w7, v7.y, acc.y);
                acc.z = fmaf(w7, v7.z, acc.z); acc.w = fmaf(w7, v7.w, acc.w);
            }
            // 2-edge steps
            for (; e + 2 <= end; e += 2) {
                int4 p = *(const int4*)(sorted + e);
                const float* xb = x + q * 4;
                float4 v0 = *(const float4*)(xb + (size_t)p.x * D);
                float4 v1 = *(const float4*)(xb + (size_t)p.z * D);
                float w0 = __int_as_float(p.y), w1 = __int_as_float(p.w);
                acc.x = fmaf(w0, v0.x, acc.x); acc.y = fmaf(w0, v0.y, acc.y);
                acc.z = fmaf(w0, v0.z, acc.z); acc.w = fmaf(w0, v0.w, acc.w);
                acc.x = fmaf(w1, v1.x, acc.x); acc.y = fmaf(w1, v1.y, acc.y);
                acc.z = fmaf(w1, v1.z, acc.z); acc.w = fmaf(w1, v1.w, acc.w);
            }
            // final odd edge
            if (e < end) {
                int2 c = sorted[e];
                float4 v = *(const float4*)(x + (size_t)c.x * D + q * 4);
                float w = __int_as_float(c.y);
                acc.x = fmaf(w, v.x, acc.x); acc.y = fmaf(w, v.y, acc.y);
                acc.z = fmaf(w, v.z, acc.z); acc.w = fmaf(w, v.w, acc.w);
            }
        }
        *(float4*)&s[r][q * 4] = acc;
    }
    __syncthreads();

    // ---- linear phase: threads 0-127 -> rows 0-3, 128-255 -> rows 4-7 ----
    int td = t & 127;
    int rbase = (t >> 7) * 4;
    float acc[4] = {0.f, 0.f, 0.f, 0.f};
#pragma unroll 4
    for (int k = 0; k < D; ++k) {
        float wt = WT[k * D + td];
#pragma unroll
        for (int r = 0; r < 4; ++r) acc[r] = fmaf(s[rbase + r][k], wt, acc[r]);
    }
    float bt = b[td];
#pragma unroll
    for (int r = 0; r < 4; ++r) acc[r] += bt;

    __syncthreads();               // done reading s as linear inputs
#pragma unroll
    for (int r = 0; r < 4; ++r) s[rbase + r][td] = acc[r];
    __syncthreads();

    // ---- LN stats: 32 threads per row ----
    {
        int rr = t >> 5, j = t & 31;
        float sum = 0.f, sq = 0.f;
#pragma unroll
        for (int i = 0; i < 4; ++i) {
            float v = s[rr][j + 32 * i];
            sum += v;
            sq = fmaf(v, v, sq);
        }
#pragma unroll
        for (int off = 16; off > 0; off >>= 1) {
            sum += __shfl_down(sum, off, 32);
            sq  += __shfl_down(sq, off, 32);
        }
        if (j == 0) {
            float mu = sum * (1.0f / D);
            float var = sq * (1.0f / D) - mu * mu;
            mu_s[rr] = mu;
            inv_s[rr] = rsqrtf(var + LN_EPS);
        }
    }
    __syncthreads();

    // ---- normalize + ReLU + store ----
    float g = gamma[td], be = beta[td];
#pragma unroll
    for (int r = 0; r < 4; ++r) {
        int row = row0 + rbase + r;
        if (row < N) {
            float y = (acc[r] - mu_s[rbase + r]) * inv_s[rbase + r] * g + be;
            out[(size_t)row * D + td] = fmaxf(y, 0.f);
        }
    }
}

// ---------------------------------------------------------------------------
// Launch
// ---------------------------------------------------------------------------
extern "C" void kernel_launch(void* const* d_in, const int* in_sizes, int n_in,
                              void* d_out, int out_size, void* d_ws, size_t ws_size,
                              hipStream_t stream) {
    const float* x        = (const float*)d_in[0];
    const float* edge_val = (const float*)d_in[1];
    const float* W        = (const float*)d_in[2];
    const float* b        = (const float*)d_in[3];
    const float* gamma    = (const float*)d_in[4];
    const float* beta     = (const float*)d_in[5];
    const int*   edge_row = (const int*)d_in[6];
    const int*   edge_col = (const int*)d_in[7];

    const int N = in_sizes[0] / D;
    const int E = in_sizes[1];

    char* ws = (char*)d_ws;
    int2*  sorted  = (int2*)ws;                 ws += (size_t)E * sizeof(int2);
    float* WT      = (float*)ws;                ws += (size_t)D * D * sizeof(float);
    int*   counts  = (int*)ws;                  ws += (size_t)N * sizeof(int);
    int*   offsets = (int*)ws;                  ws += (size_t)N * sizeof(int);
    int*   cursor  = (int*)ws;                  ws += (size_t)N * sizeof(int);
    int*   bsums   = (int*)ws;                  ws += 256 * sizeof(int);

    int nb = (N + 255) / 256;   // 196 <= 256

    setup_kernel<<<(N + 255) / 256, 256, 0, stream>>>(W, WT, counts, N);
    hist_kernel<<<((E + 7) / 8 + 255) / 256, 256, 0, stream>>>(edge_row, counts, E);
    scan1<<<nb, 256, 0, stream>>>(counts, offsets, bsums, N);
    scan23<<<nb, 256, 0, stream>>>(offsets, bsums, cursor, N, nb);
    scatter_sort<<<((E + 3) / 4 + 255) / 256, 256, 0, stream>>>(
        edge_row, edge_col, edge_val, cursor, sorted, E);
    fused_gather_linear<<<(N + RPB - 1) / RPB, 256, 0, stream>>>(
        x, sorted, offsets, WT, b, gamma, beta, (float*)d_out, N, E);
}